// Round 14
// baseline (2556.982 us; speedup 1.0000x reference)
//
#include <hip/hip_runtime.h>
#include <hip/hip_bf16.h>
#include <math.h>

// ---------------------------------------------------------------------------
// GCN 2-layer forward on MI355X.  3 launches total.
//  memset(barrier ctrs) -> FUSED [hist_lds (128 blocks x 100KB LDS packed
//  16-bit histograms, rank via LDS-atomic return) || convw]
//  -> mega_k (persistent, grid 1536 = 6 blocks/CU guaranteed co-resident):
//       P0 scan2 (replica sums -> basecum, dinv, exscan, blocksum)
//       B0; P1 all-blocks LDS scan of blocksums -> bo_lds (offsets = bo+exscan)
//       P2 fill_csr + gemm1;  B1;  P3 agg1;  B2;  P4 gemm2;  B3;  P5 agg2
// R13 analysis: sum(kernels) ~164us vs 215 total -> ~50us launch gaps; fill's
// cross-XCD scatter pinned at the ~1.8e10/s memory-side RMW wall (more blocks
// don't help), so the win is removing gaps, not more fill parallelism.
// Barriers: once-used counters, device-scope fence + atomic arrive/spin.
// R6-R8: global atomic *streams* pinned ~1.6e10/s -> all counting stays LDS.
// ---------------------------------------------------------------------------

typedef unsigned int uint32;
typedef unsigned short ushort16;
typedef __attribute__((ext_vector_type(8))) short bf16x8;
typedef __attribute__((ext_vector_type(4))) float f32x4;

#define NHB 128    // histogram blocks / replicas
#define FSPLIT 8   // fill slices per histogram chunk
#define NBLK 1536  // mega grid: 6 blocks/CU x 256 CUs (launch_bounds(256,6))

__device__ inline unsigned short f2bf_rne(float f) {
    uint32 x = __float_as_uint(f);
    uint32 r = (x + 0x7fffu + ((x >> 16) & 1u)) >> 16;
    return (unsigned short)r;
}
__device__ inline uint32 pack_bf16x2(float a, float b) {
    return (uint32)f2bf_rne(a) | ((uint32)f2bf_rne(b) << 16);
}
__device__ inline float2 unpack_bf16x2(uint32 u) {
    float2 r;
    r.x = __uint_as_float(u << 16);
    r.y = __uint_as_float(u & 0xffff0000u);
    return r;
}

// FUSED: blocks [0,NHB): per-block LDS histogram; blocks [NHB,+96): convw.
__global__ __launch_bounds__(256) void hist_conv_k(const int* __restrict__ dst, int E,
                                                   int NW, int chunk,
                                                   uint32* __restrict__ counts_pb,
                                                   ushort16* __restrict__ rankx,
                                                   const float* __restrict__ W1,
                                                   const float* __restrict__ W2,
                                                   unsigned short* __restrict__ W1t,
                                                   unsigned short* __restrict__ W2t) {
    const int tid = threadIdx.x;
    if ((int)blockIdx.x >= NHB) {
        int idx = ((int)blockIdx.x - NHB) * 256 + tid;
        if (idx < 128 * 128) {
            int ns = idx >> 7, k = idx & 127;
            int t = ns >> 4, m = ns & 15;
            int col = 32 * (t >> 1) + 2 * m + (t & 1);
            W1t[idx] = f2bf_rne(W1[k * 128 + col]);
        } else {
            int i2 = idx - 128 * 128;
            if (i2 < 64 * 128) {
                int ns = i2 >> 7, k = i2 & 127;
                int t = ns >> 4, m = ns & 15;
                int col = 32 * (t >> 1) + 2 * m + (t & 1);
                W2t[i2] = f2bf_rne(W2[k * 64 + col]);
            }
        }
        return;
    }
    extern __shared__ uint32 sh[];
    const int b = blockIdx.x;
    for (int i = tid; i < NW; i += 256) sh[i] = 0;
    __syncthreads();
    const int e0 = b * chunk;
    const int e1 = min(E, e0 + chunk);
    int e = e0 + tid;
    for (; e + 768 < e1; e += 1024) {
        int d0 = dst[e];
        int d1 = dst[e + 256];
        int d2 = dst[e + 512];
        int d3 = dst[e + 768];
        uint32 o0 = atomicAdd(&sh[d0 >> 1], (d0 & 1) ? 0x10000u : 1u);
        uint32 o1 = atomicAdd(&sh[d1 >> 1], (d1 & 1) ? 0x10000u : 1u);
        uint32 o2 = atomicAdd(&sh[d2 >> 1], (d2 & 1) ? 0x10000u : 1u);
        uint32 o3 = atomicAdd(&sh[d3 >> 1], (d3 & 1) ? 0x10000u : 1u);
        rankx[e]       = (ushort16)((d0 & 1) ? (o0 >> 16) : (o0 & 0xffffu));
        rankx[e + 256] = (ushort16)((d1 & 1) ? (o1 >> 16) : (o1 & 0xffffu));
        rankx[e + 512] = (ushort16)((d2 & 1) ? (o2 >> 16) : (o2 & 0xffffu));
        rankx[e + 768] = (ushort16)((d3 & 1) ? (o3 >> 16) : (o3 & 0xffffu));
    }
    for (; e < e1; e += 256) {
        int d = dst[e];
        uint32 o = atomicAdd(&sh[d >> 1], (d & 1) ? 0x10000u : 1u);
        rankx[e] = (ushort16)((d & 1) ? (o >> 16) : (o & 0xffffu));
    }
    __syncthreads();
    uint32* dstp = counts_pb + (size_t)b * NW;
    for (int i = tid; i < NW; i += 256) dstp[i] = sh[i];
}

// Grid barrier: once-used counter idx. Release fence -> arrive -> spin ->
// acquire fence.  All NBLK blocks are co-resident by launch_bounds math.
__device__ inline void gridbar(uint32* ctr, int idx) {
    __threadfence();
    __syncthreads();
    if (threadIdx.x == 0) {
        __hip_atomic_fetch_add(&ctr[idx], 1u, __ATOMIC_ACQ_REL, __HIP_MEMORY_SCOPE_AGENT);
        while (__hip_atomic_load(&ctr[idx], __ATOMIC_ACQUIRE, __HIP_MEMORY_SCOPE_AGENT)
               < (uint32)NBLK) {
            __builtin_amdgcn_s_sleep(1);
        }
    }
    __syncthreads();
    __threadfence();
}

// Persistent mega-kernel: scan -> bo -> fill+gemm1 -> agg1 -> gemm2 -> agg2.
__global__ __launch_bounds__(256, 6) void mega_k(
        const int* __restrict__ src, const int* __restrict__ dst,
        int E, int chunk, int N, int NB, int NW, int GB,
        const uint32* __restrict__ counts_pb,
        ushort16* __restrict__ basecum, const ushort16* __restrict__ rankx,
        int* __restrict__ exscan, int* __restrict__ blocksum,
        float* __restrict__ dinv, ushort16* __restrict__ csr_src,
        const float* __restrict__ X,
        const unsigned short* __restrict__ W1t, const unsigned short* __restrict__ W2t,
        const float* __restrict__ b1, const float* __restrict__ b2,
        uint32* __restrict__ h1u, uint32* __restrict__ h1au, uint32* __restrict__ h2u,
        float* __restrict__ out, uint32* __restrict__ ctr) {
    __shared__ int sd[256];
    __shared__ int bo_lds[256];
    const int tid = threadIdx.x;
    constexpr int NFB = NHB * FSPLIT;

    // ---- P0: scan2 (units of 256 nodes; NB=196 < NBLK so <=1 unit/block) ----
    for (int u = blockIdx.x; u < NB; u += NBLK) {
        const int n  = u * 256 + tid;
        const int nc = n < N ? n : N - 1;
        const int w  = nc >> 1;
        const bool hi = (nc & 1) != 0;
        int cum = 0;
        for (int bb = 0; bb < NHB; bb += 16) {
            uint32 wv[16];
#pragma unroll
            for (int j = 0; j < 16; ++j)
                wv[j] = counts_pb[(size_t)(bb + j) * NW + w];
#pragma unroll
            for (int j = 0; j < 16; ++j) {
                int c = hi ? (int)(wv[j] >> 16) : (int)(wv[j] & 0xffffu);
                if (n < N) basecum[(size_t)(bb + j) * N + n] = (ushort16)cum;
                cum += c;
            }
        }
        int v = (n < N) ? cum : 0;
        if (n < N) dinv[n] = rsqrtf((float)(v + 1));
        sd[tid] = v;
        __syncthreads();
        for (int off = 1; off < 256; off <<= 1) {
            int t = (tid >= off) ? sd[tid - off] : 0;
            __syncthreads();
            sd[tid] += t;
            __syncthreads();
        }
        if (n < N) exscan[n] = sd[tid] - v;
        if (n == N) exscan[N] = sd[tid];  // exclusive prefix at N (v==0 here)
        if (tid == 255) blocksum[u] = sd[255];
    }
    gridbar(ctr, 0);

    // ---- P1: every block scans blocksums into bo_lds (persists in LDS) ----
    {
        int v = (tid < NB) ? blocksum[tid] : 0;
        sd[tid] = v;
        __syncthreads();
        for (int off = 1; off < 256; off <<= 1) {
            int t = (tid >= off) ? sd[tid - off] : 0;
            __syncthreads();
            sd[tid] += t;
            __syncthreads();
        }
        bo_lds[tid] = sd[tid] - v;
        __syncthreads();
    }

    // ---- P2: fill CSR (slices) + gemm1 (tiles) ----
    for (int u = blockIdx.x; u < NFB + GB; u += NBLK) {
        if (u < NFB) {
            const int b  = u >> 3;
            const ushort16* bc = basecum + (size_t)b * N;
            const int qs = (chunk + FSPLIT - 1) / FSPLIT;
            const int e0 = b * chunk + (u & 7) * qs;
            const int e1 = min(min(E, b * chunk + chunk), e0 + qs);
            for (int e = e0 + tid; e < e1; e += 256) {
                int d = dst[e];
                int pos = bo_lds[d >> 8] + exscan[d] + (int)bc[d] + (int)rankx[e];
                csr_src[pos] = (ushort16)src[e];
            }
        } else {
            constexpr int NCOL = 128;
            constexpr int NT = NCOL / 16;
            const int wave = tid >> 6;
            const int lane = tid & 63;
            const int m16  = lane & 15;
            const int q    = lane >> 4;
            const int r0   = (u - NFB) * 64 + wave * 16;
            int arow = r0 + m16;
            if (arow >= N) arow = N - 1;
            bf16x8 afrag[4];
#pragma unroll
            for (int kb = 0; kb < 4; ++kb) {
                const float* p = &X[(size_t)arow * 128 + kb * 32 + q * 8];
                float4 u0 = *(const float4*)p;
                float4 u1 = *(const float4*)(p + 4);
                bf16x8 a;
                a[0] = (short)f2bf_rne(u0.x); a[1] = (short)f2bf_rne(u0.y);
                a[2] = (short)f2bf_rne(u0.z); a[3] = (short)f2bf_rne(u0.w);
                a[4] = (short)f2bf_rne(u1.x); a[5] = (short)f2bf_rne(u1.y);
                a[6] = (short)f2bf_rne(u1.z); a[7] = (short)f2bf_rne(u1.w);
                afrag[kb] = a;
            }
            f32x4 acc[NT];
#pragma unroll
            for (int t = 0; t < NT; ++t) acc[t] = (f32x4){0.f, 0.f, 0.f, 0.f};
#pragma unroll
            for (int t = 0; t < NT; ++t) {
                const unsigned short* Bp = &W1t[(size_t)(t * 16 + m16) * 128 + q * 8];
#pragma unroll
                for (int kb = 0; kb < 4; ++kb) {
                    bf16x8 bfrag = *(const bf16x8*)&Bp[kb * 32];
                    acc[t] = __builtin_amdgcn_mfma_f32_16x16x32_bf16(afrag[kb], bfrag,
                                                                     acc[t], 0, 0, 0);
                }
            }
#pragma unroll
            for (int i = 0; i < 4; ++i) {
                int row = r0 + q * 4 + i;
                if (row < N) {
                    float dn = dinv[row];
#pragma unroll
                    for (int uu = 0; uu < NT / 2; ++uu)
                        h1u[(size_t)row * (NCOL / 2) + uu * 16 + m16] =
                            pack_bf16x2(acc[2 * uu][i] * dn, acc[2 * uu + 1][i] * dn);
                }
            }
        }
    }
    gridbar(ctr, 1);

    // ---- P3: agg1 (4 nodes/unit, 64 lanes/node, 2ch/lane, x4 unroll) ----
    for (int u = blockIdx.x; u < (N + 3) / 4; u += NBLK) {
        const int node = u * 4 + (tid >> 6);
        const int lane = tid & 63;
        if (node < N) {
            const int start = bo_lds[node >> 8] + exscan[node];
            const int end   = bo_lds[(node + 1) >> 8] + exscan[node + 1];
            const float dn  = dinv[node];
            float2 self = unpack_bf16x2(h1u[(size_t)node * 64 + lane]);
            float ax0 = self.x, ay0 = self.y;
            float ax1 = 0.f, ay1 = 0.f, ax2 = 0.f, ay2 = 0.f, ax3 = 0.f, ay3 = 0.f;
            int p = start;
            for (; p + 3 < end; p += 4) {
                int s0 = csr_src[p];
                int s1 = csr_src[p + 1];
                int s2 = csr_src[p + 2];
                int s3 = csr_src[p + 3];
                float2 f0 = unpack_bf16x2(h1u[(size_t)s0 * 64 + lane]);
                float2 f1 = unpack_bf16x2(h1u[(size_t)s1 * 64 + lane]);
                float2 f2 = unpack_bf16x2(h1u[(size_t)s2 * 64 + lane]);
                float2 f3 = unpack_bf16x2(h1u[(size_t)s3 * 64 + lane]);
                ax0 += f0.x; ay0 += f0.y;
                ax1 += f1.x; ay1 += f1.y;
                ax2 += f2.x; ay2 += f2.y;
                ax3 += f3.x; ay3 += f3.y;
            }
            for (; p < end; ++p) {
                float2 f = unpack_bf16x2(h1u[(size_t)csr_src[p] * 64 + lane]);
                ax1 += f.x; ay1 += f.y;
            }
            float2 bb = ((const float2*)b1)[lane];
            float vx = ((ax0 + ax1) + (ax2 + ax3)) * dn + bb.x;
            float vy = ((ay0 + ay1) + (ay2 + ay3)) * dn + bb.y;
            vx = vx > 0.f ? vx : 0.f;
            vy = vy > 0.f ? vy : 0.f;
            h1au[(size_t)node * 64 + lane] = pack_bf16x2(vx, vy);
        }
    }
    gridbar(ctr, 2);

    // ---- P4: gemm2 ----
    for (int u = blockIdx.x; u < GB; u += NBLK) {
        constexpr int NCOL = 64;
        constexpr int NT = NCOL / 16;
        const int wave = tid >> 6;
        const int lane = tid & 63;
        const int m16  = lane & 15;
        const int q    = lane >> 4;
        const int r0   = u * 64 + wave * 16;
        int arow = r0 + m16;
        if (arow >= N) arow = N - 1;
        const unsigned short* Xb = (const unsigned short*)h1au;
        bf16x8 afrag[4];
#pragma unroll
        for (int kb = 0; kb < 4; ++kb)
            afrag[kb] = *(const bf16x8*)&Xb[(size_t)arow * 128 + kb * 32 + q * 8];
        f32x4 acc[NT];
#pragma unroll
        for (int t = 0; t < NT; ++t) acc[t] = (f32x4){0.f, 0.f, 0.f, 0.f};
#pragma unroll
        for (int t = 0; t < NT; ++t) {
            const unsigned short* Bp = &W2t[(size_t)(t * 16 + m16) * 128 + q * 8];
#pragma unroll
            for (int kb = 0; kb < 4; ++kb) {
                bf16x8 bfrag = *(const bf16x8*)&Bp[kb * 32];
                acc[t] = __builtin_amdgcn_mfma_f32_16x16x32_bf16(afrag[kb], bfrag,
                                                                 acc[t], 0, 0, 0);
            }
        }
#pragma unroll
        for (int i = 0; i < 4; ++i) {
            int row = r0 + q * 4 + i;
            if (row < N) {
                float dn = dinv[row];
#pragma unroll
                for (int uu = 0; uu < NT / 2; ++uu)
                    h2u[(size_t)row * (NCOL / 2) + uu * 16 + m16] =
                        pack_bf16x2(acc[2 * uu][i] * dn, acc[2 * uu + 1][i] * dn);
            }
        }
    }
    gridbar(ctr, 3);

    // ---- P5: agg2 + log_softmax (8 nodes/unit, 32 lanes/node) ----
    for (int u = blockIdx.x; u < (N + 7) / 8; u += NBLK) {
        const int node = u * 8 + (tid >> 5);
        const int l    = tid & 31;
        if (node < N) {
            const int start = bo_lds[node >> 8] + exscan[node];
            const int end   = bo_lds[(node + 1) >> 8] + exscan[node + 1];
            const float dn  = dinv[node];
            float2 self = unpack_bf16x2(h2u[(size_t)node * 32 + l]);
            float ax0 = self.x, ay0 = self.y;
            float ax1 = 0.f, ay1 = 0.f, ax2 = 0.f, ay2 = 0.f, ax3 = 0.f, ay3 = 0.f;
            int p = start;
            for (; p + 3 < end; p += 4) {
                int s0 = csr_src[p];
                int s1 = csr_src[p + 1];
                int s2 = csr_src[p + 2];
                int s3 = csr_src[p + 3];
                float2 f0 = unpack_bf16x2(h2u[(size_t)s0 * 32 + l]);
                float2 f1 = unpack_bf16x2(h2u[(size_t)s1 * 32 + l]);
                float2 f2 = unpack_bf16x2(h2u[(size_t)s2 * 32 + l]);
                float2 f3 = unpack_bf16x2(h2u[(size_t)s3 * 32 + l]);
                ax0 += f0.x; ay0 += f0.y;
                ax1 += f1.x; ay1 += f1.y;
                ax2 += f2.x; ay2 += f2.y;
                ax3 += f3.x; ay3 += f3.y;
            }
            for (; p < end; ++p) {
                float2 f = unpack_bf16x2(h2u[(size_t)csr_src[p] * 32 + l]);
                ax1 += f.x; ay1 += f.y;
            }
            float2 bb = ((const float2*)b2)[l];
            float vx = ((ax0 + ax1) + (ax2 + ax3)) * dn + bb.x;
            float vy = ((ay0 + ay1) + (ay2 + ay3)) * dn + bb.y;
            float m = fmaxf(vx, vy);
#pragma unroll
            for (int off = 16; off > 0; off >>= 1) m = fmaxf(m, __shfl_xor(m, off, 64));
            float ex = __expf(vx - m) + __expf(vy - m);
            float ssum = ex;
#pragma unroll
            for (int off = 16; off > 0; off >>= 1) ssum += __shfl_xor(ssum, off, 64);
            float lse = m + __logf(ssum);
            float2 o = {vx - lse, vy - lse};
            ((float2*)out)[(size_t)node * 32 + l] = o;
        }
    }
}

extern "C" void kernel_launch(void* const* d_in, const int* in_sizes, int n_in,
                              void* d_out, int out_size, void* d_ws, size_t ws_size,
                              hipStream_t stream) {
    const float* x  = (const float*)d_in[0];
    const int*   ei = (const int*)d_in[1];
    const float* W1 = (const float*)d_in[2];
    const float* b1 = (const float*)d_in[3];
    const float* W2 = (const float*)d_in[4];
    const float* b2 = (const float*)d_in[5];
    float* out = (float*)d_out;

    const int N = in_sizes[0] / 128;  // 50000
    const int E = in_sizes[1] / 2;    // 800000
    const int* src = ei;
    const int* dst = ei + E;
    const int NB = (N + 255) / 256;        // 196
    const int NW = (N + 1) / 2;            // 25000 packed count words
    const int chunk = (E + NHB - 1) / NHB; // 6250 edges per hist block
    const int GB = (N + 63) / 64;          // 782 gemm tiles

    char* ws = (char*)d_ws;
    auto alloc = [&](size_t bytes) -> char* {
        char* p = ws;
        ws += (bytes + 255) & ~(size_t)255;
        return p;
    };
    unsigned short* h1  = (unsigned short*)alloc((size_t)N * 128 * 2);
    unsigned short* h1a = (unsigned short*)alloc((size_t)N * 128 * 2);
    unsigned short* h2  = (unsigned short*)alloc((size_t)N * 64 * 2);
    uint32* counts_pb = (uint32*)alloc((size_t)NHB * NW * 4);
    ushort16* basecum = (ushort16*)alloc((size_t)NHB * N * 2);
    ushort16* rankx   = (ushort16*)alloc((size_t)E * 2);
    ushort16* csr_src = (ushort16*)alloc((size_t)E * 2);
    float* dinv     = (float*)alloc((size_t)N * 4);
    int*   exscan   = (int*)alloc((size_t)(N + 1) * 4);
    int*   blocksum = (int*)alloc((size_t)NB * 4);
    uint32* ctr     = (uint32*)alloc(4 * 4);
    unsigned short* W1t = (unsigned short*)alloc(128 * 128 * 2);
    unsigned short* W2t = (unsigned short*)alloc(64 * 128 * 2);

    const int CB = (128 * 128 + 64 * 128 + 255) / 256;  // 96 convw blocks

    hipMemsetAsync(ctr, 0, 4 * 4, stream);
    hist_conv_k<<<NHB + CB, 256, NW * 4, stream>>>(dst, E, NW, chunk, counts_pb, rankx,
                                                   W1, W2, W1t, W2t);
    mega_k<<<NBLK, 256, 0, stream>>>(src, dst, E, chunk, N, NB, NW, GB,
                                     counts_pb, basecum, rankx, exscan, blocksum,
                                     dinv, csr_src, x, W1t, W2t, b1, b2,
                                     (uint32*)h1, (uint32*)h1a, (uint32*)h2,
                                     out, ctr);
}